// Round 11
// baseline (191.654 us; speedup 1.0000x reference)
//
#include <hip/hip_runtime.h>

#define BSZ 512
#define NNODE 30
#define KNBR 15
#define HID 128
#define MTOT (BSZ*NNODE)   // 15360

typedef __attribute__((ext_vector_type(8))) __bf16 bf16x8;
typedef __attribute__((ext_vector_type(4))) float f32x4;

__device__ __forceinline__ float frelu(float x){ return x > 0.f ? x : 0.f; }

__device__ __forceinline__ void node_coords(const float* __restrict__ st,
                                            const float* __restrict__ ac,
                                            int b, int n, int qsel, float c[4]) {
    if (qsel == 0) {
        c[0] = st[b*60 + 2*n];     c[1] = st[b*60 + 2*n + 1];
        c[2] = ac[b*60 + 2*n];     c[3] = ac[b*60 + 2*n + 1];
    } else {
        int base = 4*n;
        if (base < 60) {
            c[0]=st[b*60+base]; c[1]=st[b*60+base+1]; c[2]=st[b*60+base+2]; c[3]=st[b*60+base+3];
        } else {
            int a = base - 60;
            c[0]=ac[b*60+a]; c[1]=ac[b*60+a+1]; c[2]=ac[b*60+a+2]; c[3]=ac[b*60+a+3];
        }
    }
}

// prep: weight bf16 conversions + cls bias folds for both Qs.
__global__ void k_prep(const float* __restrict__ Wa,  const float* __restrict__ Wb,
                       const float* __restrict__ Wca1,const float* __restrict__ Wca2,
                       const float* __restrict__ ba,
                       const float* __restrict__ emb1,const float* __restrict__ emb2,
                       __bf16* __restrict__ Wc16, __bf16* __restrict__ Wb16,
                       __bf16* __restrict__ Wca16_1, __bf16* __restrict__ Wca16_2,
                       float* __restrict__ cls1A, float* __restrict__ cls1B,
                       float* __restrict__ cls2A, float* __restrict__ cls2B) {
    int blk = blockIdx.x;
    if (blk < 320) {
        int t = blk*256 + threadIdx.x;
        if (t < 32768) {
            int o = t >> 7, h = t & 127;
            float v = (o < 128) ? (Wa[o*388 + h] - Wa[o*388 + 194 + h])
                                : Wa[(o-128)*388 + 194 + h];
            Wc16[t] = (__bf16)v;
        } else if (t < 49152) { int u = t - 32768; Wb16[u]    = (__bf16)Wb[u]; }
        else if (t < 65536)   { int u = t - 49152; Wca16_1[u] = (__bf16)Wca1[u]; }
        else                  { int u = t - 65536; Wca16_2[u] = (__bf16)Wca2[u]; }
    } else {
        int o = threadIdx.x;
        if (o >= 128) return;
        const float* emb = (blk == 320) ? emb1  : emb2;
        float* cA        = (blk == 320) ? cls1A : cls2A;
        float* cB        = (blk == 320) ? cls1B : cls2B;
        for (int c = 0; c < 3; ++c) {
            float sA = ba[o], sB = 0.f;
            for (int e = 0; e < 64; ++e) {
                float r  = frelu(emb[c*64 + e]);
                float wl = Wa[o*388 + 128 + e];
                float wr = Wa[o*388 + 194 + 128 + e];
                sA += (wl - wr) * r;
                sB += wr * r;
            }
            cA[c*128 + o] = sA;
            cB[c*128 + o] = sB;
        }
    }
}

// Fully fused critic, both Qs in one grid: block = one (sample, q). 256 thr / 4 waves.
// LDS overlay: [El | Vf] share bytes 0..8703 (Vf dead after phase 2);
// [coords | redh] share bytes 26944.. (coords dead after phase 1).
__global__ void __launch_bounds__(256, 8) k_fused(
        const float* __restrict__ st, const float* __restrict__ ac,
        const float* __restrict__ Wi1, const float* __restrict__ bi1,
        const float* __restrict__ Wi2, const float* __restrict__ bi2,
        const __bf16* __restrict__ Wc16,
        const float* __restrict__ cls1A, const float* __restrict__ cls1B,
        const float* __restrict__ cls2A, const float* __restrict__ cls2B,
        const __bf16* __restrict__ Wb16, const float* __restrict__ bb,
        const __bf16* __restrict__ Wca16_1, const float* __restrict__ bca1,
        const float* __restrict__ Wcb1, const float* __restrict__ bcb1,
        const __bf16* __restrict__ Wca16_2, const float* __restrict__ bca2,
        const float* __restrict__ Wcb2, const float* __restrict__ bcb2,
        float* __restrict__ out) {
    __shared__ __align__(16) char smem[27424];
    __bf16 (*Vf)[4][4][16][8] = reinterpret_cast<__bf16 (*)[4][4][16][8]>(smem); // [2][..]
    __bf16* El   = (__bf16*)smem;                 // 32*136 bf16 = 8704 B (rows 30/31 pad)
    __bf16* Al   = (__bf16*)(smem + 8704);        // 30*136 bf16
    __bf16* Bl   = (__bf16*)(smem + 16864);       // 30*136 bf16
    int*    idxs = (int*)(smem + 25024);          // 30*16 ints
    float (*coords)[4] = (float(*)[4])(smem + 26944);  // 30*4 f32
    float (*redh)[16]  = (float(*)[16])(smem + 26944); // 4*16 f32 (overlay)

    int tid  = threadIdx.x;
    int lane = tid & 63, wid = tid >> 6;
    int l15  = lane & 15, g = (lane >> 4) & 3;
    int bid  = blockIdx.x;
    int q    = bid >> 9, b = bid & 511;

    const float* Wi   = q ? Wi2 : Wi1;
    const float* bi   = q ? bi2 : bi1;
    const float* clsA = q ? cls2A : cls1A;
    const float* clsB = q ? cls2B : cls1B;
    const __bf16* Wca16 = q ? Wca16_2 : Wca16_1;
    const float* bca  = q ? bca2 : bca1;
    const float* Wcb  = q ? Wcb2 : Wcb1;
    const float* bcb  = q ? bcb2 : bcb1;

    // phase 0: coords
    if (tid < 30) {
        float c[4]; node_coords(st, ac, b, tid, q, c);
        coords[tid][0]=c[0]; coords[tid][1]=c[1]; coords[tid][2]=c[2]; coords[tid][3]=c[3];
    }
    __syncthreads();

    // phase 1: kNN on wave0 lanes 0..29; V (frag layout, vectorized) on threads 32..255
    if (tid < 30) {
        int i = tid;
        float ci0=coords[i][0], ci1=coords[i][1], ci2=coords[i][2], ci3=coords[i][3];
        float d[30];
        #pragma unroll
        for (int j = 0; j < 30; ++j) {
            float d0 = ci0-coords[j][0], d1 = ci1-coords[j][1];
            float d2 = ci2-coords[j][2], d3 = ci3-coords[j][3];
            d[j] = d0*d0 + d1*d1 + d2*d2 + d3*d3;
        }
        unsigned mask = 1u << i;
        for (int k = 0; k < KNBR; ++k) {
            float best = 3.4e38f; int bj = 0;
            #pragma unroll
            for (int j = 0; j < 30; ++j) {
                bool ok = !((mask >> j) & 1u) && (d[j] < best);
                if (ok) { best = d[j]; bj = j; }
            }
            mask |= 1u << bj;
            idxs[i*16 + k] = bj;
        }
        idxs[i*16 + 15] = idxs[i*16];      // dup edge 0 into row 15
    } else if (tid >= 32) {
        for (int it = tid - 32; it < 512; it += 224) {
            int row = it & 15, g2 = (it >> 4) & 3, kk2 = (it >> 6) & 3, mt2 = it >> 8;
            int m = mt2*16 + row;
            bf16x8 v8;
            if (m < 30) {
                float c0=coords[m][0], c1=coords[m][1], c2=coords[m][2], c3=coords[m][3];
                #pragma unroll
                for (int e = 0; e < 8; ++e) {
                    int h = kk2*32 + g2*8 + e;
                    v8[e] = (__bf16)frelu(bi[h] + Wi[h*4+0]*c0 + Wi[h*4+1]*c1
                                                + Wi[h*4+2]*c2 + Wi[h*4+3]*c3);
                }
            } else {
                #pragma unroll
                for (int e = 0; e < 8; ++e) v8[e] = (__bf16)0.f;
            }
            *(bf16x8*)&Vf[mt2][kk2][g2][row][0] = v8;
        }
    }
    __syncthreads();

    // phase 2: [A;B] = V @ Wcomb^T + cls bias -> bf16 LDS. wave: mt = wid&1, half = wid>>1
    {
        int mt = wid & 1, half = wid >> 1;
        bf16x8 af[4];
        #pragma unroll
        for (int kk = 0; kk < 4; ++kk) af[kk] = *(const bf16x8*)&Vf[mt][kk][g][l15][0];
        f32x4 acc[8];
        #pragma unroll
        for (int nc = 0; nc < 8; ++nc) acc[nc] = (f32x4){0.f,0.f,0.f,0.f};
        #pragma unroll
        for (int nc = 0; nc < 8; ++nc) {
            int o256 = half*128 + nc*16 + l15;
            bf16x8 wf[4];
            #pragma unroll
            for (int kk = 0; kk < 4; ++kk)
                wf[kk] = *(const bf16x8*)(Wc16 + o256*128 + kk*32 + g*8);
            #pragma unroll
            for (int kk = 0; kk < 4; ++kk)
                acc[nc] = __builtin_amdgcn_mfma_f32_16x16x32_bf16(af[kk], wf[kk], acc[nc], 0, 0, 0);
        }
        const float* cls = half ? clsB : clsA;
        __bf16* dst = half ? Bl : Al;
        #pragma unroll
        for (int nc = 0; nc < 8; ++nc) {
            #pragma unroll
            for (int r = 0; r < 4; ++r) {
                int m = mt*16 + g*4 + r;
                if (m < 30) {
                    int o = nc*16 + l15;
                    int cat = m / 10;
                    dst[m*136 + o] = (__bf16)(acc[nc][r] + cls[cat*128 + o]);
                }
            }
        }
    }
    __syncthreads();

    // phase 3: edge MFMA, oc-chunked (2 x 4 oc), weight frags 64 VGPRs.
    {
        for (int ch = 0; ch < 2; ++ch) {
            bf16x8 wbf[4][4];
            #pragma unroll
            for (int oc = 0; oc < 4; ++oc)
                #pragma unroll
                for (int kk = 0; kk < 4; ++kk)
                    wbf[oc][kk] = *(const bf16x8*)(Wb16 + ((ch*4+oc)*16 + l15)*128 + kk*32 + g*8);
            float bbv[4];
            #pragma unroll
            for (int oc = 0; oc < 4; ++oc) bbv[oc] = bb[(ch*4+oc)*16 + l15];

            for (int i = wid; i < 30; i += 4) {
                int nb = idxs[i*16 + l15];
                bf16x8 hf[4];
                #pragma unroll
                for (int kk = 0; kk < 4; ++kk) {
                    bf16x8 pa = *(const bf16x8*)&Al[i*136  + kk*32 + g*8];
                    bf16x8 pb = *(const bf16x8*)&Bl[nb*136 + kk*32 + g*8];
                    bf16x8 h;
                    #pragma unroll
                    for (int e = 0; e < 8; ++e)
                        h[e] = (__bf16)frelu((float)pa[e] + (float)pb[e]);
                    hf[kk] = h;
                }
                f32x4 acc[4];
                #pragma unroll
                for (int oc = 0; oc < 4; ++oc) acc[oc] = (f32x4){0.f,0.f,0.f,0.f};
                #pragma unroll
                for (int kk = 0; kk < 4; ++kk)
                    #pragma unroll
                    for (int oc = 0; oc < 4; ++oc)
                        acc[oc] = __builtin_amdgcn_mfma_f32_16x16x32_bf16(hf[kk], wbf[oc][kk], acc[oc], 0, 0, 0);
                #pragma unroll
                for (int oc = 0; oc < 4; ++oc) {
                    float v = fmaxf(fmaxf(acc[oc][0], acc[oc][1]), fmaxf(acc[oc][2], acc[oc][3]));
                    v = fmaxf(v, __shfl_xor(v, 16));
                    v = fmaxf(v, __shfl_xor(v, 32));
                    if (g == 0) El[i*136 + (ch*4+oc)*16 + l15] = (__bf16)frelu(v + bbv[oc]);
                }
            }
        }
        if (tid < 136) ((unsigned*)El)[2040 + tid] = 0u;   // zero rows 30,31
    }
    __syncthreads();

    // phase 4: head. G = relu(Wca @ E + bca); q_m = G . Wcb + bcb
    {
        int mt = wid & 1, half = wid >> 1;
        bf16x8 ef[4];
        #pragma unroll
        for (int kk = 0; kk < 4; ++kk)
            ef[kk] = *(const bf16x8*)&El[(mt*16 + l15)*136 + kk*32 + g*8];
        float s[4] = {0.f, 0.f, 0.f, 0.f};
        #pragma unroll
        for (int nc = 0; nc < 4; ++nc) {
            int o = half*64 + nc*16 + l15;
            bf16x8 wf[4];
            #pragma unroll
            for (int kk = 0; kk < 4; ++kk)
                wf[kk] = *(const bf16x8*)(Wca16 + o*128 + kk*32 + g*8);
            f32x4 a = (f32x4){0.f,0.f,0.f,0.f};
            #pragma unroll
            for (int kk = 0; kk < 4; ++kk)
                a = __builtin_amdgcn_mfma_f32_16x16x32_bf16(ef[kk], wf[kk], a, 0, 0, 0);
            float bcav = bca[o], wcbv = Wcb[o];
            #pragma unroll
            for (int r = 0; r < 4; ++r) s[r] += frelu(a[r] + bcav) * wcbv;
        }
        #pragma unroll
        for (int r = 0; r < 4; ++r) {
            s[r] += __shfl_xor(s[r], 1);
            s[r] += __shfl_xor(s[r], 2);
            s[r] += __shfl_xor(s[r], 4);
            s[r] += __shfl_xor(s[r], 8);
        }
        if (l15 == 0) {
            #pragma unroll
            for (int r = 0; r < 4; ++r) redh[wid][g*4 + r] = s[r];
        }
    }
    __syncthreads();
    if (tid < 30) {
        int mt = tid >> 4, mr = tid & 15;
        out[q*MTOT + b*30 + tid] = redh[mt][mr] + redh[mt+2][mr] + bcb[0];
    }
}

extern "C" void kernel_launch(void* const* d_in, const int* in_sizes, int n_in,
                              void* d_out, int out_size, void* d_ws, size_t ws_size,
                              hipStream_t stream) {
    const float* state  = (const float*)d_in[0];
    const float* action = (const float*)d_in[1];
    const float* W_init1= (const float*)d_in[2];
    const float* b_init1= (const float*)d_in[3];
    const float* emb1   = (const float*)d_in[4];
    const float* W_m1a  = (const float*)d_in[5];
    const float* b_m1a  = (const float*)d_in[6];
    const float* W_m1b  = (const float*)d_in[7];
    const float* b_m1b  = (const float*)d_in[8];
    const float* W_c1a  = (const float*)d_in[9];
    const float* b_c1a  = (const float*)d_in[10];
    const float* W_c1b  = (const float*)d_in[11];
    const float* b_c1b  = (const float*)d_in[12];
    const float* W_init2= (const float*)d_in[13];
    const float* b_init2= (const float*)d_in[14];
    const float* emb2   = (const float*)d_in[15];
    const float* W_c2a  = (const float*)d_in[16];
    const float* b_c2a  = (const float*)d_in[17];
    const float* W_c2b  = (const float*)d_in[18];
    const float* b_c2b  = (const float*)d_in[19];

    __bf16* Wc16    = (__bf16*)d_ws;            // 32768
    __bf16* Wb16    = Wc16 + 32768;             // 16384
    __bf16* Wca16_1 = Wb16 + 16384;             // 16384
    __bf16* Wca16_2 = Wca16_1 + 16384;          // 16384
    float*  cls1A   = (float*)(Wca16_2 + 16384);
    float*  cls1B   = cls1A + 384;
    float*  cls2A   = cls1B + 384;
    float*  cls2B   = cls2A + 384;
    float*  out     = (float*)d_out;

    k_prep<<<322, 256, 0, stream>>>(W_m1a, W_m1b, W_c1a, W_c2a, b_m1a, emb1, emb2,
                                    Wc16, Wb16, Wca16_1, Wca16_2,
                                    cls1A, cls1B, cls2A, cls2B);

    k_fused<<<2*BSZ, 256, 0, stream>>>(state, action,
                                       W_init1, b_init1, W_init2, b_init2,
                                       Wc16, cls1A, cls1B, cls2A, cls2B,
                                       Wb16, b_m1b,
                                       Wca16_1, b_c1a, W_c1b, b_c1b,
                                       Wca16_2, b_c2a, W_c2b, b_c2b,
                                       out);
}

// Round 13
// 172.701 us; speedup vs baseline: 1.1097x; 1.1097x over previous
//
#include <hip/hip_runtime.h>

#define BSZ 512
#define NNODE 30
#define KNBR 15
#define HID 128
#define MTOT (BSZ*NNODE)   // 15360

typedef __attribute__((ext_vector_type(8))) __bf16 bf16x8;
typedef __attribute__((ext_vector_type(4))) float f32x4;

__device__ __forceinline__ float frelu(float x){ return x > 0.f ? x : 0.f; }

__device__ __forceinline__ void node_coords(const float* __restrict__ st,
                                            const float* __restrict__ ac,
                                            int b, int n, int qsel, float c[4]) {
    if (qsel == 0) {
        c[0] = st[b*60 + 2*n];     c[1] = st[b*60 + 2*n + 1];
        c[2] = ac[b*60 + 2*n];     c[3] = ac[b*60 + 2*n + 1];
    } else {
        int base = 4*n;
        if (base < 60) {
            c[0]=st[b*60+base]; c[1]=st[b*60+base+1]; c[2]=st[b*60+base+2]; c[3]=st[b*60+base+3];
        } else {
            int a = base - 60;
            c[0]=ac[b*60+a]; c[1]=ac[b*60+a+1]; c[2]=ac[b*60+a+2]; c[3]=ac[b*60+a+3];
        }
    }
}

// prep: weight bf16 conversions + cls bias folds for both Qs.
__global__ void k_prep(const float* __restrict__ Wa,  const float* __restrict__ Wb,
                       const float* __restrict__ Wca1,const float* __restrict__ Wca2,
                       const float* __restrict__ ba,
                       const float* __restrict__ emb1,const float* __restrict__ emb2,
                       __bf16* __restrict__ Wc16, __bf16* __restrict__ Wb16,
                       __bf16* __restrict__ Wca16_1, __bf16* __restrict__ Wca16_2,
                       float* __restrict__ cls1A, float* __restrict__ cls1B,
                       float* __restrict__ cls2A, float* __restrict__ cls2B) {
    int blk = blockIdx.x;
    if (blk < 320) {
        int t = blk*256 + threadIdx.x;
        if (t < 32768) {
            int o = t >> 7, h = t & 127;
            float v = (o < 128) ? (Wa[o*388 + h] - Wa[o*388 + 194 + h])
                                : Wa[(o-128)*388 + 194 + h];
            Wc16[t] = (__bf16)v;
        } else if (t < 49152) { int u = t - 32768; Wb16[u]    = (__bf16)Wb[u]; }
        else if (t < 65536)   { int u = t - 49152; Wca16_1[u] = (__bf16)Wca1[u]; }
        else                  { int u = t - 65536; Wca16_2[u] = (__bf16)Wca2[u]; }
    } else {
        int o = threadIdx.x;
        if (o >= 128) return;
        const float* emb = (blk == 320) ? emb1  : emb2;
        float* cA        = (blk == 320) ? cls1A : cls2A;
        float* cB        = (blk == 320) ? cls1B : cls2B;
        for (int c = 0; c < 3; ++c) {
            float sA = ba[o], sB = 0.f;
            for (int e = 0; e < 64; ++e) {
                float r  = frelu(emb[c*64 + e]);
                float wl = Wa[o*388 + 128 + e];
                float wr = Wa[o*388 + 194 + 128 + e];
                sA += (wl - wr) * r;
                sB += wr * r;
            }
            cA[c*128 + o] = sA;
            cB[c*128 + o] = sB;
        }
    }
}

// Fully fused critic, both Qs in one grid: block = one (sample, q). 256 thr / 4 waves.
// LDS overlays as unions of DISTINCT shared objects (keeps alias analysis):
//   {Vf | El}: Vf dead after phase 2, El first written phase 3 (barrier-separated)
//   {coords | redh}: coords dead after phase 1, redh written phase 4
__global__ void __launch_bounds__(256, 4) k_fused(
        const float* __restrict__ st, const float* __restrict__ ac,
        const float* __restrict__ Wi1, const float* __restrict__ bi1,
        const float* __restrict__ Wi2, const float* __restrict__ bi2,
        const __bf16* __restrict__ Wc16,
        const float* __restrict__ cls1A, const float* __restrict__ cls1B,
        const float* __restrict__ cls2A, const float* __restrict__ cls2B,
        const __bf16* __restrict__ Wb16, const float* __restrict__ bb,
        const __bf16* __restrict__ Wca16_1, const float* __restrict__ bca1,
        const float* __restrict__ Wcb1, const float* __restrict__ bcb1,
        const __bf16* __restrict__ Wca16_2, const float* __restrict__ bca2,
        const float* __restrict__ Wcb2, const float* __restrict__ bcb2,
        float* __restrict__ out) {
    __shared__ __align__(16) union UVE {
        __bf16 Vf[2][4][4][16][8];     // 8192 B, phase 1-2
        __bf16 El[32*136];             // 8704 B, phase 3-4 (rows 30/31 pad)
    } uVE;
    __shared__ __align__(16) __bf16 Al[30*136];
    __shared__ __align__(16) __bf16 Bl[30*136];
    __shared__ int idxs[30*16];
    __shared__ __align__(16) union UCR {
        float coords[30][4];           // phase 0-1
        float redh[4][16];             // phase 4
    } uCR;

    int tid  = threadIdx.x;
    int lane = tid & 63, wid = tid >> 6;
    int l15  = lane & 15, g = (lane >> 4) & 3;
    int bid  = blockIdx.x;
    int q    = bid >> 9, b = bid & 511;

    const float* Wi   = q ? Wi2 : Wi1;
    const float* bi   = q ? bi2 : bi1;
    const float* clsA = q ? cls2A : cls1A;
    const float* clsB = q ? cls2B : cls1B;
    const __bf16* Wca16 = q ? Wca16_2 : Wca16_1;
    const float* bca  = q ? bca2 : bca1;
    const float* Wcb  = q ? Wcb2 : Wcb1;
    const float* bcb  = q ? bcb2 : bcb1;

    // phase 0: coords
    if (tid < 30) {
        float c[4]; node_coords(st, ac, b, tid, q, c);
        uCR.coords[tid][0]=c[0]; uCR.coords[tid][1]=c[1];
        uCR.coords[tid][2]=c[2]; uCR.coords[tid][3]=c[3];
    }
    __syncthreads();

    // phase 1: kNN on wave0 lanes 0..29; V (frag layout, vectorized) on threads 32..255
    if (tid < 30) {
        int i = tid;
        float ci0=uCR.coords[i][0], ci1=uCR.coords[i][1], ci2=uCR.coords[i][2], ci3=uCR.coords[i][3];
        float d[30];
        #pragma unroll
        for (int j = 0; j < 30; ++j) {
            float d0 = ci0-uCR.coords[j][0], d1 = ci1-uCR.coords[j][1];
            float d2 = ci2-uCR.coords[j][2], d3 = ci3-uCR.coords[j][3];
            d[j] = d0*d0 + d1*d1 + d2*d2 + d3*d3;
        }
        unsigned mask = 1u << i;
        for (int k = 0; k < KNBR; ++k) {
            float best = 3.4e38f; int bj = 0;
            #pragma unroll
            for (int j = 0; j < 30; ++j) {
                bool ok = !((mask >> j) & 1u) && (d[j] < best);
                if (ok) { best = d[j]; bj = j; }
            }
            mask |= 1u << bj;
            idxs[i*16 + k] = bj;
        }
        idxs[i*16 + 15] = idxs[i*16];      // dup edge 0 into row 15
    } else if (tid >= 32) {
        for (int it = tid - 32; it < 512; it += 224) {
            int row = it & 15, g2 = (it >> 4) & 3, kk2 = (it >> 6) & 3, mt2 = it >> 8;
            int m = mt2*16 + row;
            bf16x8 v8;
            if (m < 30) {
                float c0=uCR.coords[m][0], c1=uCR.coords[m][1],
                      c2=uCR.coords[m][2], c3=uCR.coords[m][3];
                #pragma unroll
                for (int e = 0; e < 8; ++e) {
                    int h = kk2*32 + g2*8 + e;
                    v8[e] = (__bf16)frelu(bi[h] + Wi[h*4+0]*c0 + Wi[h*4+1]*c1
                                                + Wi[h*4+2]*c2 + Wi[h*4+3]*c3);
                }
            } else {
                #pragma unroll
                for (int e = 0; e < 8; ++e) v8[e] = (__bf16)0.f;
            }
            *(bf16x8*)&uVE.Vf[mt2][kk2][g2][row][0] = v8;
        }
    }
    __syncthreads();

    // phase 2: [A;B] = V @ Wcomb^T + cls bias -> bf16 LDS. wave: mt = wid&1, half = wid>>1
    {
        int mt = wid & 1, half = wid >> 1;
        bf16x8 af[4];
        #pragma unroll
        for (int kk = 0; kk < 4; ++kk) af[kk] = *(const bf16x8*)&uVE.Vf[mt][kk][g][l15][0];
        f32x4 acc[8];
        #pragma unroll
        for (int nc = 0; nc < 8; ++nc) acc[nc] = (f32x4){0.f,0.f,0.f,0.f};
        #pragma unroll
        for (int nc = 0; nc < 8; ++nc) {
            int o256 = half*128 + nc*16 + l15;
            bf16x8 wf[4];
            #pragma unroll
            for (int kk = 0; kk < 4; ++kk)
                wf[kk] = *(const bf16x8*)(Wc16 + o256*128 + kk*32 + g*8);
            #pragma unroll
            for (int kk = 0; kk < 4; ++kk)
                acc[nc] = __builtin_amdgcn_mfma_f32_16x16x32_bf16(af[kk], wf[kk], acc[nc], 0, 0, 0);
        }
        const float* cls = half ? clsB : clsA;
        __bf16* dst = half ? Bl : Al;
        #pragma unroll
        for (int nc = 0; nc < 8; ++nc) {
            #pragma unroll
            for (int r = 0; r < 4; ++r) {
                int m = mt*16 + g*4 + r;
                if (m < 30) {
                    int o = nc*16 + l15;
                    int cat = m / 10;
                    dst[m*136 + o] = (__bf16)(acc[nc][r] + cls[cat*128 + o]);
                }
            }
        }
    }
    __syncthreads();

    // phase 3: edge MFMA, oc-chunked (2 x 4 oc), weight frags 64 VGPRs.
    {
        for (int ch = 0; ch < 2; ++ch) {
            bf16x8 wbf[4][4];
            #pragma unroll
            for (int oc = 0; oc < 4; ++oc)
                #pragma unroll
                for (int kk = 0; kk < 4; ++kk)
                    wbf[oc][kk] = *(const bf16x8*)(Wb16 + ((ch*4+oc)*16 + l15)*128 + kk*32 + g*8);
            float bbv[4];
            #pragma unroll
            for (int oc = 0; oc < 4; ++oc) bbv[oc] = bb[(ch*4+oc)*16 + l15];

            for (int i = wid; i < 30; i += 4) {
                int nb = idxs[i*16 + l15];
                bf16x8 hf[4];
                #pragma unroll
                for (int kk = 0; kk < 4; ++kk) {
                    bf16x8 pa = *(const bf16x8*)&Al[i*136  + kk*32 + g*8];
                    bf16x8 pb = *(const bf16x8*)&Bl[nb*136 + kk*32 + g*8];
                    bf16x8 h;
                    #pragma unroll
                    for (int e = 0; e < 8; ++e)
                        h[e] = (__bf16)frelu((float)pa[e] + (float)pb[e]);
                    hf[kk] = h;
                }
                f32x4 acc[4];
                #pragma unroll
                for (int oc = 0; oc < 4; ++oc) acc[oc] = (f32x4){0.f,0.f,0.f,0.f};
                #pragma unroll
                for (int kk = 0; kk < 4; ++kk)
                    #pragma unroll
                    for (int oc = 0; oc < 4; ++oc)
                        acc[oc] = __builtin_amdgcn_mfma_f32_16x16x32_bf16(hf[kk], wbf[oc][kk], acc[oc], 0, 0, 0);
                #pragma unroll
                for (int oc = 0; oc < 4; ++oc) {
                    float v = fmaxf(fmaxf(acc[oc][0], acc[oc][1]), fmaxf(acc[oc][2], acc[oc][3]));
                    v = fmaxf(v, __shfl_xor(v, 16));
                    v = fmaxf(v, __shfl_xor(v, 32));
                    if (g == 0) uVE.El[i*136 + (ch*4+oc)*16 + l15] = (__bf16)frelu(v + bbv[oc]);
                }
            }
        }
        if (tid < 136) ((unsigned*)uVE.El)[2040 + tid] = 0u;   // zero rows 30,31
    }
    __syncthreads();

    // phase 4: head. G = relu(Wca @ E + bca); q_m = G . Wcb + bcb
    {
        int mt = wid & 1, half = wid >> 1;
        bf16x8 ef[4];
        #pragma unroll
        for (int kk = 0; kk < 4; ++kk)
            ef[kk] = *(const bf16x8*)&uVE.El[(mt*16 + l15)*136 + kk*32 + g*8];
        float s[4] = {0.f, 0.f, 0.f, 0.f};
        #pragma unroll
        for (int nc = 0; nc < 4; ++nc) {
            int o = half*64 + nc*16 + l15;
            bf16x8 wf[4];
            #pragma unroll
            for (int kk = 0; kk < 4; ++kk)
                wf[kk] = *(const bf16x8*)(Wca16 + o*128 + kk*32 + g*8);
            f32x4 a = (f32x4){0.f,0.f,0.f,0.f};
            #pragma unroll
            for (int kk = 0; kk < 4; ++kk)
                a = __builtin_amdgcn_mfma_f32_16x16x32_bf16(ef[kk], wf[kk], a, 0, 0, 0);
            float bcav = bca[o], wcbv = Wcb[o];
            #pragma unroll
            for (int r = 0; r < 4; ++r) s[r] += frelu(a[r] + bcav) * wcbv;
        }
        #pragma unroll
        for (int r = 0; r < 4; ++r) {
            s[r] += __shfl_xor(s[r], 1);
            s[r] += __shfl_xor(s[r], 2);
            s[r] += __shfl_xor(s[r], 4);
            s[r] += __shfl_xor(s[r], 8);
        }
        if (l15 == 0) {
            #pragma unroll
            for (int r = 0; r < 4; ++r) uCR.redh[wid][g*4 + r] = s[r];
        }
    }
    __syncthreads();
    if (tid < 30) {
        int mt = tid >> 4, mr = tid & 15;
        out[q*MTOT + b*30 + tid] = uCR.redh[mt][mr] + uCR.redh[mt+2][mr] + bcb[0];
    }
}

extern "C" void kernel_launch(void* const* d_in, const int* in_sizes, int n_in,
                              void* d_out, int out_size, void* d_ws, size_t ws_size,
                              hipStream_t stream) {
    const float* state  = (const float*)d_in[0];
    const float* action = (const float*)d_in[1];
    const float* W_init1= (const float*)d_in[2];
    const float* b_init1= (const float*)d_in[3];
    const float* emb1   = (const float*)d_in[4];
    const float* W_m1a  = (const float*)d_in[5];
    const float* b_m1a  = (const float*)d_in[6];
    const float* W_m1b  = (const float*)d_in[7];
    const float* b_m1b  = (const float*)d_in[8];
    const float* W_c1a  = (const float*)d_in[9];
    const float* b_c1a  = (const float*)d_in[10];
    const float* W_c1b  = (const float*)d_in[11];
    const float* b_c1b  = (const float*)d_in[12];
    const float* W_init2= (const float*)d_in[13];
    const float* b_init2= (const float*)d_in[14];
    const float* emb2   = (const float*)d_in[15];
    const float* W_c2a  = (const float*)d_in[16];
    const float* b_c2a  = (const float*)d_in[17];
    const float* W_c2b  = (const float*)d_in[18];
    const float* b_c2b  = (const float*)d_in[19];

    __bf16* Wc16    = (__bf16*)d_ws;            // 32768
    __bf16* Wb16    = Wc16 + 32768;             // 16384
    __bf16* Wca16_1 = Wb16 + 16384;             // 16384
    __bf16* Wca16_2 = Wca16_1 + 16384;          // 16384
    float*  cls1A   = (float*)(Wca16_2 + 16384);
    float*  cls1B   = cls1A + 384;
    float*  cls2A   = cls1B + 384;
    float*  cls2B   = cls2A + 384;
    float*  out     = (float*)d_out;

    k_prep<<<322, 256, 0, stream>>>(W_m1a, W_m1b, W_c1a, W_c2a, b_m1a, emb1, emb2,
                                    Wc16, Wb16, Wca16_1, Wca16_2,
                                    cls1A, cls1B, cls2A, cls2B);

    k_fused<<<2*BSZ, 256, 0, stream>>>(state, action,
                                       W_init1, b_init1, W_init2, b_init2,
                                       Wc16, cls1A, cls1B, cls2A, cls2B,
                                       Wb16, b_m1b,
                                       Wca16_1, b_c1a, W_c1b, b_c1b,
                                       Wca16_2, b_c2a, W_c2b, b_c2b,
                                       out);
}

// Round 14
// 172.033 us; speedup vs baseline: 1.1141x; 1.0039x over previous
//
#include <hip/hip_runtime.h>

#define BSZ 512
#define NNODE 30
#define KNBR 15
#define HID 128
#define MTOT (BSZ*NNODE)   // 15360

typedef __attribute__((ext_vector_type(8))) __bf16 bf16x8;
typedef __attribute__((ext_vector_type(4))) float f32x4;

__device__ __forceinline__ float frelu(float x){ return x > 0.f ? x : 0.f; }

__device__ __forceinline__ void node_coords(const float* __restrict__ st,
                                            const float* __restrict__ ac,
                                            int b, int n, int qsel, float c[4]) {
    if (qsel == 0) {
        c[0] = st[b*60 + 2*n];     c[1] = st[b*60 + 2*n + 1];
        c[2] = ac[b*60 + 2*n];     c[3] = ac[b*60 + 2*n + 1];
    } else {
        int base = 4*n;
        if (base < 60) {
            c[0]=st[b*60+base]; c[1]=st[b*60+base+1]; c[2]=st[b*60+base+2]; c[3]=st[b*60+base+3];
        } else {
            int a = base - 60;
            c[0]=ac[b*60+a]; c[1]=ac[b*60+a+1]; c[2]=ac[b*60+a+2]; c[3]=ac[b*60+a+3];
        }
    }
}

// prep: weight bf16 conversions + cls bias folds for both Qs.
__global__ void k_prep(const float* __restrict__ Wa,  const float* __restrict__ Wb,
                       const float* __restrict__ Wca1,const float* __restrict__ Wca2,
                       const float* __restrict__ ba,
                       const float* __restrict__ emb1,const float* __restrict__ emb2,
                       __bf16* __restrict__ Wc16, __bf16* __restrict__ Wb16,
                       __bf16* __restrict__ Wca16_1, __bf16* __restrict__ Wca16_2,
                       float* __restrict__ cls1A, float* __restrict__ cls1B,
                       float* __restrict__ cls2A, float* __restrict__ cls2B) {
    int blk = blockIdx.x;
    if (blk < 320) {
        int t = blk*256 + threadIdx.x;
        if (t < 32768) {
            int o = t >> 7, h = t & 127;
            float v = (o < 128) ? (Wa[o*388 + h] - Wa[o*388 + 194 + h])
                                : Wa[(o-128)*388 + 194 + h];
            Wc16[t] = (__bf16)v;
        } else if (t < 49152) { int u = t - 32768; Wb16[u]    = (__bf16)Wb[u]; }
        else if (t < 65536)   { int u = t - 49152; Wca16_1[u] = (__bf16)Wca1[u]; }
        else                  { int u = t - 65536; Wca16_2[u] = (__bf16)Wca2[u]; }
    } else {
        int o = threadIdx.x;
        if (o >= 128) return;
        const float* emb = (blk == 320) ? emb1  : emb2;
        float* cA        = (blk == 320) ? cls1A : cls2A;
        float* cB        = (blk == 320) ? cls1B : cls2B;
        for (int c = 0; c < 3; ++c) {
            float sA = ba[o], sB = 0.f;
            for (int e = 0; e < 64; ++e) {
                float r  = frelu(emb[c*64 + e]);
                float wl = Wa[o*388 + 128 + e];
                float wr = Wa[o*388 + 194 + 128 + e];
                sA += (wl - wr) * r;
                sB += wr * r;
            }
            cA[c*128 + o] = sA;
            cB[c*128 + o] = sB;
        }
    }
}

// Fully fused critic, both Qs in one grid: block = one (sample, q). 256 thr / 4 waves.
// kNN via parallel rank-select (exact top_k ordering: strict-less + lower-index ties).
// LDS overlays (unions of distinct objects, barrier-separated lifetimes):
//   {Vf | El}, {dist | Al}, {coords | redh}
__global__ void __launch_bounds__(256, 4) k_fused(
        const float* __restrict__ st, const float* __restrict__ ac,
        const float* __restrict__ Wi1, const float* __restrict__ bi1,
        const float* __restrict__ Wi2, const float* __restrict__ bi2,
        const __bf16* __restrict__ Wc16,
        const float* __restrict__ cls1A, const float* __restrict__ cls1B,
        const float* __restrict__ cls2A, const float* __restrict__ cls2B,
        const __bf16* __restrict__ Wb16, const float* __restrict__ bb,
        const __bf16* __restrict__ Wca16_1, const float* __restrict__ bca1,
        const float* __restrict__ Wcb1, const float* __restrict__ bcb1,
        const __bf16* __restrict__ Wca16_2, const float* __restrict__ bca2,
        const float* __restrict__ Wcb2, const float* __restrict__ bcb2,
        float* __restrict__ out) {
    __shared__ __align__(16) union UVE {
        __bf16 Vf[2][4][4][16][8];     // 8192 B, phase 1-2
        __bf16 El[32*136];             // 8704 B, phase 3-4 (rows 30/31 pad)
    } uVE;
    __shared__ __align__(16) union UDA {
        float  dist[30*33];            // 3960 B, phase 1 (stride 33: bank spread)
        __bf16 Al[32*136];             // 8704 B, phase 2-3 (rows 30/31 junk, never read)
    } uDA;
    __shared__ __align__(16) __bf16 Bl[32*136];
    __shared__ int idxs[30*16];
    __shared__ __align__(16) union UCR {
        float coords[30][4];           // phase 0-1
        float redh[4][16];             // phase 4
    } uCR;

    int tid  = threadIdx.x;
    int lane = tid & 63, wid = tid >> 6;
    int l15  = lane & 15, g = (lane >> 4) & 3;
    int bid  = blockIdx.x;
    int q    = bid >> 9, b = bid & 511;

    const float* Wi   = q ? Wi2 : Wi1;
    const float* bi   = q ? bi2 : bi1;
    const float* clsA = q ? cls2A : cls1A;
    const float* clsB = q ? cls2B : cls1B;
    const __bf16* Wca16 = q ? Wca16_2 : Wca16_1;
    const float* bca  = q ? bca2 : bca1;
    const float* Wcb  = q ? Wcb2 : Wcb1;
    const float* bcb  = q ? bcb2 : bcb1;

    // phase 0: coords
    if (tid < 30) {
        float c[4]; node_coords(st, ac, b, tid, q, c);
        uCR.coords[tid][0]=c[0]; uCR.coords[tid][1]=c[1];
        uCR.coords[tid][2]=c[2]; uCR.coords[tid][3]=c[3];
    }
    __syncthreads();

    // phase 1a: all 900 pairwise distances -> LDS; V fragments (all threads share)
    for (int t = tid; t < 900; t += 256) {
        int i = t / 30, j = t - i*30;
        float d0 = uCR.coords[i][0]-uCR.coords[j][0];
        float d1 = uCR.coords[i][1]-uCR.coords[j][1];
        float d2 = uCR.coords[i][2]-uCR.coords[j][2];
        float d3 = uCR.coords[i][3]-uCR.coords[j][3];
        uDA.dist[i*33 + j] = d0*d0 + d1*d1 + d2*d2 + d3*d3;
    }
    for (int it = tid; it < 512; it += 256) {
        int row = it & 15, g2 = (it >> 4) & 3, kk2 = (it >> 6) & 3, mt2 = it >> 8;
        int m = mt2*16 + row;
        bf16x8 v8;
        if (m < 30) {
            float c0=uCR.coords[m][0], c1=uCR.coords[m][1],
                  c2=uCR.coords[m][2], c3=uCR.coords[m][3];
            #pragma unroll
            for (int e = 0; e < 8; ++e) {
                int h = kk2*32 + g2*8 + e;
                v8[e] = (__bf16)frelu(bi[h] + Wi[h*4+0]*c0 + Wi[h*4+1]*c1
                                            + Wi[h*4+2]*c2 + Wi[h*4+3]*c3);
            }
        } else {
            #pragma unroll
            for (int e = 0; e < 8; ++e) v8[e] = (__bf16)0.f;
        }
        *(bf16x8*)&uVE.Vf[mt2][kk2][g2][row][0] = v8;
    }
    __syncthreads();

    // phase 1b: rank-select -> idxs. rank(j for i) = #{j'!=i : d_j' < d_j or (== and j'<j)}
    for (int t = tid; t < 900; t += 256) {
        int i = t / 30, j = t - i*30;
        if (j != i) {
            float dj = uDA.dist[i*33 + j];
            int rank = 0;
            #pragma unroll
            for (int j2 = 0; j2 < 30; ++j2) {
                float dv = uDA.dist[i*33 + j2];
                bool less = (dv < dj) || (dv == dj && j2 < j);
                rank += (j2 != i && less) ? 1 : 0;
            }
            if (rank < KNBR) idxs[i*16 + rank] = j;
        }
    }
    __syncthreads();

    // phase 2: [A;B] = V @ Wcomb^T + cls bias -> bf16 LDS. wave: mt = wid&1, half = wid>>1
    if (tid < 30) idxs[tid*16 + 15] = idxs[tid*16];   // dup edge 0 into row 15
    {
        int mt = wid & 1, half = wid >> 1;
        bf16x8 af[4];
        #pragma unroll
        for (int kk = 0; kk < 4; ++kk) af[kk] = *(const bf16x8*)&uVE.Vf[mt][kk][g][l15][0];
        f32x4 acc[8];
        #pragma unroll
        for (int nc = 0; nc < 8; ++nc) acc[nc] = (f32x4){0.f,0.f,0.f,0.f};
        #pragma unroll
        for (int nc = 0; nc < 8; ++nc) {
            int o256 = half*128 + nc*16 + l15;
            bf16x8 wf[4];
            #pragma unroll
            for (int kk = 0; kk < 4; ++kk)
                wf[kk] = *(const bf16x8*)(Wc16 + o256*128 + kk*32 + g*8);
            #pragma unroll
            for (int kk = 0; kk < 4; ++kk)
                acc[nc] = __builtin_amdgcn_mfma_f32_16x16x32_bf16(af[kk], wf[kk], acc[nc], 0, 0, 0);
        }
        const float* cls = half ? clsB : clsA;
        __bf16* dst = half ? Bl : uDA.Al;
        #pragma unroll
        for (int nc = 0; nc < 8; ++nc) {
            #pragma unroll
            for (int r = 0; r < 4; ++r) {
                int m = mt*16 + g*4 + r;
                int o = nc*16 + l15;
                int cat = (m < 30) ? (m / 10) : 0;
                dst[m*136 + o] = (__bf16)(acc[nc][r] + cls[cat*128 + o]);
            }
        }
    }
    __syncthreads();

    // phase 3: edge MFMA. wave = (i-parity, oc-half); wbf loaded once (64 VGPR).
    {
        int ip = wid & 1, oh = wid >> 1;
        bf16x8 wbf[4][4];
        #pragma unroll
        for (int c = 0; c < 4; ++c)
            #pragma unroll
            for (int kk = 0; kk < 4; ++kk)
                wbf[c][kk] = *(const bf16x8*)(Wb16 + ((oh*4+c)*16 + l15)*128 + kk*32 + g*8);
        float bbv[4];
        #pragma unroll
        for (int c = 0; c < 4; ++c) bbv[c] = bb[(oh*4+c)*16 + l15];

        for (int i = ip; i < 30; i += 2) {
            int nb = idxs[i*16 + l15];
            bf16x8 hf[4];
            #pragma unroll
            for (int kk = 0; kk < 4; ++kk) {
                bf16x8 pa = *(const bf16x8*)&uDA.Al[i*136  + kk*32 + g*8];
                bf16x8 pb = *(const bf16x8*)&Bl[nb*136 + kk*32 + g*8];
                bf16x8 h;
                #pragma unroll
                for (int e = 0; e < 8; ++e)
                    h[e] = (__bf16)frelu((float)pa[e] + (float)pb[e]);
                hf[kk] = h;
            }
            f32x4 acc[4];
            #pragma unroll
            for (int c = 0; c < 4; ++c) acc[c] = (f32x4){0.f,0.f,0.f,0.f};
            #pragma unroll
            for (int kk = 0; kk < 4; ++kk)
                #pragma unroll
                for (int c = 0; c < 4; ++c)
                    acc[c] = __builtin_amdgcn_mfma_f32_16x16x32_bf16(hf[kk], wbf[c][kk], acc[c], 0, 0, 0);
            #pragma unroll
            for (int c = 0; c < 4; ++c) {
                float v = fmaxf(fmaxf(acc[c][0], acc[c][1]), fmaxf(acc[c][2], acc[c][3]));
                v = fmaxf(v, __shfl_xor(v, 16));
                v = fmaxf(v, __shfl_xor(v, 32));
                if (g == 0) uVE.El[i*136 + (oh*4+c)*16 + l15] = (__bf16)frelu(v + bbv[c]);
            }
        }
        if (tid < 136) ((unsigned*)uVE.El)[2040 + tid] = 0u;   // zero rows 30,31
    }
    __syncthreads();

    // phase 4: head. G = relu(Wca @ E + bca); q_m = G . Wcb + bcb
    {
        int mt = wid & 1, half = wid >> 1;
        bf16x8 ef[4];
        #pragma unroll
        for (int kk = 0; kk < 4; ++kk)
            ef[kk] = *(const bf16x8*)&uVE.El[(mt*16 + l15)*136 + kk*32 + g*8];
        float s[4] = {0.f, 0.f, 0.f, 0.f};
        #pragma unroll
        for (int nc = 0; nc < 4; ++nc) {
            int o = half*64 + nc*16 + l15;
            bf16x8 wf[4];
            #pragma unroll
            for (int kk = 0; kk < 4; ++kk)
                wf[kk] = *(const bf16x8*)(Wca16 + o*128 + kk*32 + g*8);
            f32x4 a = (f32x4){0.f,0.f,0.f,0.f};
            #pragma unroll
            for (int kk = 0; kk < 4; ++kk)
                a = __builtin_amdgcn_mfma_f32_16x16x32_bf16(ef[kk], wf[kk], a, 0, 0, 0);
            float bcav = bca[o], wcbv = Wcb[o];
            #pragma unroll
            for (int r = 0; r < 4; ++r) s[r] += frelu(a[r] + bcav) * wcbv;
        }
        #pragma unroll
        for (int r = 0; r < 4; ++r) {
            s[r] += __shfl_xor(s[r], 1);
            s[r] += __shfl_xor(s[r], 2);
            s[r] += __shfl_xor(s[r], 4);
            s[r] += __shfl_xor(s[r], 8);
        }
        if (l15 == 0) {
            #pragma unroll
            for (int r = 0; r < 4; ++r) uCR.redh[wid][g*4 + r] = s[r];
        }
    }
    __syncthreads();
    if (tid < 30) {
        int mt = tid >> 4, mr = tid & 15;
        out[q*MTOT + b*30 + tid] = uCR.redh[mt][mr] + uCR.redh[mt+2][mr] + bcb[0];
    }
}

extern "C" void kernel_launch(void* const* d_in, const int* in_sizes, int n_in,
                              void* d_out, int out_size, void* d_ws, size_t ws_size,
                              hipStream_t stream) {
    const float* state  = (const float*)d_in[0];
    const float* action = (const float*)d_in[1];
    const float* W_init1= (const float*)d_in[2];
    const float* b_init1= (const float*)d_in[3];
    const float* emb1   = (const float*)d_in[4];
    const float* W_m1a  = (const float*)d_in[5];
    const float* b_m1a  = (const float*)d_in[6];
    const float* W_m1b  = (const float*)d_in[7];
    const float* b_m1b  = (const float*)d_in[8];
    const float* W_c1a  = (const float*)d_in[9];
    const float* b_c1a  = (const float*)d_in[10];
    const float* W_c1b  = (const float*)d_in[11];
    const float* b_c1b  = (const float*)d_in[12];
    const float* W_init2= (const float*)d_in[13];
    const float* b_init2= (const float*)d_in[14];
    const float* emb2   = (const float*)d_in[15];
    const float* W_c2a  = (const float*)d_in[16];
    const float* b_c2a  = (const float*)d_in[17];
    const float* W_c2b  = (const float*)d_in[18];
    const float* b_c2b  = (const float*)d_in[19];

    __bf16* Wc16    = (__bf16*)d_ws;            // 32768
    __bf16* Wb16    = Wc16 + 32768;             // 16384
    __bf16* Wca16_1 = Wb16 + 16384;             // 16384
    __bf16* Wca16_2 = Wca16_1 + 16384;          // 16384
    float*  cls1A   = (float*)(Wca16_2 + 16384);
    float*  cls1B   = cls1A + 384;
    float*  cls2A   = cls1B + 384;
    float*  cls2B   = cls2A + 384;
    float*  out     = (float*)d_out;

    k_prep<<<322, 256, 0, stream>>>(W_m1a, W_m1b, W_c1a, W_c2a, b_m1a, emb1, emb2,
                                    Wc16, Wb16, Wca16_1, Wca16_2,
                                    cls1A, cls1B, cls2A, cls2B);

    k_fused<<<2*BSZ, 256, 0, stream>>>(state, action,
                                       W_init1, b_init1, W_init2, b_init2,
                                       Wc16, cls1A, cls1B, cls2A, cls2B,
                                       Wb16, b_m1b,
                                       Wca16_1, b_c1a, W_c1b, b_c1b,
                                       Wca16_2, b_c2a, W_c2b, b_c2b,
                                       out);
}

// Round 15
// 162.432 us; speedup vs baseline: 1.1799x; 1.0591x over previous
//
#include <hip/hip_runtime.h>

#define BSZ 512
#define NNODE 30
#define KNBR 15
#define HID 128
#define MTOT (BSZ*NNODE)   // 15360

typedef __attribute__((ext_vector_type(8))) _Float16 f16x8;
typedef __attribute__((ext_vector_type(4))) float f32x4;

__device__ __forceinline__ float frelu(float x){ return x > 0.f ? x : 0.f; }

__device__ __forceinline__ void node_coords(const float* __restrict__ st,
                                            const float* __restrict__ ac,
                                            int b, int n, int qsel, float c[4]) {
    if (qsel == 0) {
        c[0] = st[b*60 + 2*n];     c[1] = st[b*60 + 2*n + 1];
        c[2] = ac[b*60 + 2*n];     c[3] = ac[b*60 + 2*n + 1];
    } else {
        int base = 4*n;
        if (base < 60) {
            c[0]=st[b*60+base]; c[1]=st[b*60+base+1]; c[2]=st[b*60+base+2]; c[3]=st[b*60+base+3];
        } else {
            int a = base - 60;
            c[0]=ac[b*60+a]; c[1]=ac[b*60+a+1]; c[2]=ac[b*60+a+2]; c[3]=ac[b*60+a+3];
        }
    }
}

// prep: weight fp16 conversions + cls bias folds for both Qs.
__global__ void k_prep(const float* __restrict__ Wa,  const float* __restrict__ Wb,
                       const float* __restrict__ Wca1,const float* __restrict__ Wca2,
                       const float* __restrict__ ba,
                       const float* __restrict__ emb1,const float* __restrict__ emb2,
                       _Float16* __restrict__ Wc16, _Float16* __restrict__ Wb16,
                       _Float16* __restrict__ Wca16_1, _Float16* __restrict__ Wca16_2,
                       float* __restrict__ cls1A, float* __restrict__ cls1B,
                       float* __restrict__ cls2A, float* __restrict__ cls2B) {
    int blk = blockIdx.x;
    if (blk < 320) {
        int t = blk*256 + threadIdx.x;
        if (t < 32768) {
            int o = t >> 7, h = t & 127;
            float v = (o < 128) ? (Wa[o*388 + h] - Wa[o*388 + 194 + h])
                                : Wa[(o-128)*388 + 194 + h];
            Wc16[t] = (_Float16)v;
        } else if (t < 49152) { int u = t - 32768; Wb16[u]    = (_Float16)Wb[u]; }
        else if (t < 65536)   { int u = t - 49152; Wca16_1[u] = (_Float16)Wca1[u]; }
        else                  { int u = t - 65536; Wca16_2[u] = (_Float16)Wca2[u]; }
    } else {
        int o = threadIdx.x;
        if (o >= 128) return;
        const float* emb = (blk == 320) ? emb1  : emb2;
        float* cA        = (blk == 320) ? cls1A : cls2A;
        float* cB        = (blk == 320) ? cls1B : cls2B;
        for (int c = 0; c < 3; ++c) {
            float sA = ba[o], sB = 0.f;
            for (int e = 0; e < 64; ++e) {
                float r  = frelu(emb[c*64 + e]);
                float wl = Wa[o*388 + 128 + e];
                float wr = Wa[o*388 + 194 + 128 + e];
                sA += (wl - wr) * r;
                sB += wr * r;
            }
            cA[c*128 + o] = sA;
            cB[c*128 + o] = sB;
        }
    }
}

// Fully fused critic, both Qs in one grid: block = one (sample, q). 256 thr / 4 waves.
// All low-precision storage/matmul in fp16 (packed VALU for H-build).
// LDS overlays (unions of distinct objects, barrier-separated lifetimes):
//   {Vf | El}, {dist | Al}, {coords | redh}
__global__ void __launch_bounds__(256, 4) k_fused(
        const float* __restrict__ st, const float* __restrict__ ac,
        const float* __restrict__ Wi1, const float* __restrict__ bi1,
        const float* __restrict__ Wi2, const float* __restrict__ bi2,
        const _Float16* __restrict__ Wc16,
        const float* __restrict__ cls1A, const float* __restrict__ cls1B,
        const float* __restrict__ cls2A, const float* __restrict__ cls2B,
        const _Float16* __restrict__ Wb16, const float* __restrict__ bb,
        const _Float16* __restrict__ Wca16_1, const float* __restrict__ bca1,
        const float* __restrict__ Wcb1, const float* __restrict__ bcb1,
        const _Float16* __restrict__ Wca16_2, const float* __restrict__ bca2,
        const float* __restrict__ Wcb2, const float* __restrict__ bcb2,
        float* __restrict__ out) {
    __shared__ __align__(16) union UVE {
        _Float16 Vf[2][4][4][16][8];   // 8192 B, phase 1-2
        _Float16 El[32*136];           // 8704 B, phase 3-4 (rows 30/31 pad)
    } uVE;
    __shared__ __align__(16) union UDA {
        float    dist[30*33];          // 3960 B, phase 1 (stride 33: bank spread)
        _Float16 Al[32*136];           // 8704 B, phase 2-3 (rows 30/31 junk, never read)
    } uDA;
    __shared__ __align__(16) _Float16 Bl[32*136];
    __shared__ int idxs[30*16];
    __shared__ __align__(16) union UCR {
        float coords[30][4];           // phase 0-1
        float redh[4][16];             // phase 4
    } uCR;

    int tid  = threadIdx.x;
    int lane = tid & 63, wid = tid >> 6;
    int l15  = lane & 15, g = (lane >> 4) & 3;
    int bid  = blockIdx.x;
    int q    = bid >> 9, b = bid & 511;

    const float* Wi   = q ? Wi2 : Wi1;
    const float* bi   = q ? bi2 : bi1;
    const float* clsA = q ? cls2A : cls1A;
    const float* clsB = q ? cls2B : cls1B;
    const _Float16* Wca16 = q ? Wca16_2 : Wca16_1;
    const float* bca  = q ? bca2 : bca1;
    const float* Wcb  = q ? Wcb2 : Wcb1;
    const float* bcb  = q ? bcb2 : bcb1;

    // phase 0: coords
    if (tid < 30) {
        float c[4]; node_coords(st, ac, b, tid, q, c);
        uCR.coords[tid][0]=c[0]; uCR.coords[tid][1]=c[1];
        uCR.coords[tid][2]=c[2]; uCR.coords[tid][3]=c[3];
    }
    __syncthreads();

    // phase 1a: all 900 pairwise distances -> LDS; V fragments (all threads share)
    for (int t = tid; t < 900; t += 256) {
        int i = t / 30, j = t - i*30;
        float d0 = uCR.coords[i][0]-uCR.coords[j][0];
        float d1 = uCR.coords[i][1]-uCR.coords[j][1];
        float d2 = uCR.coords[i][2]-uCR.coords[j][2];
        float d3 = uCR.coords[i][3]-uCR.coords[j][3];
        uDA.dist[i*33 + j] = d0*d0 + d1*d1 + d2*d2 + d3*d3;
    }
    for (int it = tid; it < 512; it += 256) {
        int row = it & 15, g2 = (it >> 4) & 3, kk2 = (it >> 6) & 3, mt2 = it >> 8;
        int m = mt2*16 + row;
        f16x8 v8;
        if (m < 30) {
            float c0=uCR.coords[m][0], c1=uCR.coords[m][1],
                  c2=uCR.coords[m][2], c3=uCR.coords[m][3];
            #pragma unroll
            for (int e = 0; e < 8; ++e) {
                int h = kk2*32 + g2*8 + e;
                v8[e] = (_Float16)frelu(bi[h] + Wi[h*4+0]*c0 + Wi[h*4+1]*c1
                                              + Wi[h*4+2]*c2 + Wi[h*4+3]*c3);
            }
        } else {
            #pragma unroll
            for (int e = 0; e < 8; ++e) v8[e] = (_Float16)0.f;
        }
        *(f16x8*)&uVE.Vf[mt2][kk2][g2][row][0] = v8;
    }
    __syncthreads();

    // phase 1b: rank-select -> idxs. rank(j for i) = #{j'!=i : d_j' < d_j or (== and j'<j)}
    for (int t = tid; t < 900; t += 256) {
        int i = t / 30, j = t - i*30;
        if (j != i) {
            float dj = uDA.dist[i*33 + j];
            int rank = 0;
            #pragma unroll
            for (int j2 = 0; j2 < 30; ++j2) {
                float dv = uDA.dist[i*33 + j2];
                bool less = (dv < dj) || (dv == dj && j2 < j);
                rank += (j2 != i && less) ? 1 : 0;
            }
            if (rank < KNBR) idxs[i*16 + rank] = j;
        }
    }
    __syncthreads();

    // phase 2: [A;B] = V @ Wcomb^T + cls bias -> fp16 LDS. wave: mt = wid&1, half = wid>>1
    if (tid < 30) idxs[tid*16 + 15] = idxs[tid*16];   // dup edge 0 into row 15
    {
        int mt = wid & 1, half = wid >> 1;
        f16x8 af[4];
        #pragma unroll
        for (int kk = 0; kk < 4; ++kk) af[kk] = *(const f16x8*)&uVE.Vf[mt][kk][g][l15][0];
        f32x4 acc[8];
        #pragma unroll
        for (int nc = 0; nc < 8; ++nc) acc[nc] = (f32x4){0.f,0.f,0.f,0.f};
        #pragma unroll
        for (int nc = 0; nc < 8; ++nc) {
            int o256 = half*128 + nc*16 + l15;
            f16x8 wf[4];
            #pragma unroll
            for (int kk = 0; kk < 4; ++kk)
                wf[kk] = *(const f16x8*)(Wc16 + o256*128 + kk*32 + g*8);
            #pragma unroll
            for (int kk = 0; kk < 4; ++kk)
                acc[nc] = __builtin_amdgcn_mfma_f32_16x16x32_f16(af[kk], wf[kk], acc[nc], 0, 0, 0);
        }
        const float* cls = half ? clsB : clsA;
        _Float16* dst = half ? Bl : uDA.Al;
        #pragma unroll
        for (int nc = 0; nc < 8; ++nc) {
            #pragma unroll
            for (int r = 0; r < 4; ++r) {
                int m = mt*16 + g*4 + r;
                int o = nc*16 + l15;
                int cat = (m < 30) ? (m / 10) : 0;
                dst[m*136 + o] = (_Float16)(acc[nc][r] + cls[cat*128 + o]);
            }
        }
    }
    __syncthreads();

    // phase 3: edge MFMA. wave = (i-parity, oc-half); wbf loaded once (64 VGPR).
    // H-build: packed fp16 add + max (v_pk_add_f16 / v_pk_max_f16), no conversions.
    {
        int ip = wid & 1, oh = wid >> 1;
        f16x8 wbf[4][4];
        #pragma unroll
        for (int c = 0; c < 4; ++c)
            #pragma unroll
            for (int kk = 0; kk < 4; ++kk)
                wbf[c][kk] = *(const f16x8*)(Wb16 + ((oh*4+c)*16 + l15)*128 + kk*32 + g*8);
        float bbv[4];
        #pragma unroll
        for (int c = 0; c < 4; ++c) bbv[c] = bb[(oh*4+c)*16 + l15];

        const f16x8 zero8 = (f16x8)(_Float16)0.f;
        for (int i = ip; i < 30; i += 2) {
            int nb = idxs[i*16 + l15];
            f16x8 hf[4];
            #pragma unroll
            for (int kk = 0; kk < 4; ++kk) {
                f16x8 pa = *(const f16x8*)&uDA.Al[i*136  + kk*32 + g*8];
                f16x8 pb = *(const f16x8*)&Bl[nb*136 + kk*32 + g*8];
                f16x8 s = pa + pb;
                hf[kk] = __builtin_elementwise_max(s, zero8);
            }
            f32x4 acc[4];
            #pragma unroll
            for (int c = 0; c < 4; ++c) acc[c] = (f32x4){0.f,0.f,0.f,0.f};
            #pragma unroll
            for (int kk = 0; kk < 4; ++kk)
                #pragma unroll
                for (int c = 0; c < 4; ++c)
                    acc[c] = __builtin_amdgcn_mfma_f32_16x16x32_f16(hf[kk], wbf[c][kk], acc[c], 0, 0, 0);
            #pragma unroll
            for (int c = 0; c < 4; ++c) {
                float v = fmaxf(fmaxf(acc[c][0], acc[c][1]), fmaxf(acc[c][2], acc[c][3]));
                v = fmaxf(v, __shfl_xor(v, 16));
                v = fmaxf(v, __shfl_xor(v, 32));
                if (g == 0) uVE.El[i*136 + (oh*4+c)*16 + l15] = (_Float16)frelu(v + bbv[c]);
            }
        }
        if (tid < 136) ((unsigned*)uVE.El)[2040 + tid] = 0u;   // zero rows 30,31
    }
    __syncthreads();

    // phase 4: head. G = relu(Wca @ E + bca); q_m = G . Wcb + bcb
    {
        int mt = wid & 1, half = wid >> 1;
        f16x8 ef[4];
        #pragma unroll
        for (int kk = 0; kk < 4; ++kk)
            ef[kk] = *(const f16x8*)&uVE.El[(mt*16 + l15)*136 + kk*32 + g*8];
        float s[4] = {0.f, 0.f, 0.f, 0.f};
        #pragma unroll
        for (int nc = 0; nc < 4; ++nc) {
            int o = half*64 + nc*16 + l15;
            f16x8 wf[4];
            #pragma unroll
            for (int kk = 0; kk < 4; ++kk)
                wf[kk] = *(const f16x8*)(Wca16 + o*128 + kk*32 + g*8);
            f32x4 a = (f32x4){0.f,0.f,0.f,0.f};
            #pragma unroll
            for (int kk = 0; kk < 4; ++kk)
                a = __builtin_amdgcn_mfma_f32_16x16x32_f16(ef[kk], wf[kk], a, 0, 0, 0);
            float bcav = bca[o], wcbv = Wcb[o];
            #pragma unroll
            for (int r = 0; r < 4; ++r) s[r] += frelu(a[r] + bcav) * wcbv;
        }
        #pragma unroll
        for (int r = 0; r < 4; ++r) {
            s[r] += __shfl_xor(s[r], 1);
            s[r] += __shfl_xor(s[r], 2);
            s[r] += __shfl_xor(s[r], 4);
            s[r] += __shfl_xor(s[r], 8);
        }
        if (l15 == 0) {
            #pragma unroll
            for (int r = 0; r < 4; ++r) uCR.redh[wid][g*4 + r] = s[r];
        }
    }
    __syncthreads();
    if (tid < 30) {
        int mt = tid >> 4, mr = tid & 15;
        out[q*MTOT + b*30 + tid] = uCR.redh[mt][mr] + uCR.redh[mt+2][mr] + bcb[0];
    }
}

extern "C" void kernel_launch(void* const* d_in, const int* in_sizes, int n_in,
                              void* d_out, int out_size, void* d_ws, size_t ws_size,
                              hipStream_t stream) {
    const float* state  = (const float*)d_in[0];
    const float* action = (const float*)d_in[1];
    const float* W_init1= (const float*)d_in[2];
    const float* b_init1= (const float*)d_in[3];
    const float* emb1   = (const float*)d_in[4];
    const float* W_m1a  = (const float*)d_in[5];
    const float* b_m1a  = (const float*)d_in[6];
    const float* W_m1b  = (const float*)d_in[7];
    const float* b_m1b  = (const float*)d_in[8];
    const float* W_c1a  = (const float*)d_in[9];
    const float* b_c1a  = (const float*)d_in[10];
    const float* W_c1b  = (const float*)d_in[11];
    const float* b_c1b  = (const float*)d_in[12];
    const float* W_init2= (const float*)d_in[13];
    const float* b_init2= (const float*)d_in[14];
    const float* emb2   = (const float*)d_in[15];
    const float* W_c2a  = (const float*)d_in[16];
    const float* b_c2a  = (const float*)d_in[17];
    const float* W_c2b  = (const float*)d_in[18];
    const float* b_c2b  = (const float*)d_in[19];

    _Float16* Wc16    = (_Float16*)d_ws;          // 32768
    _Float16* Wb16    = Wc16 + 32768;             // 16384
    _Float16* Wca16_1 = Wb16 + 16384;             // 16384
    _Float16* Wca16_2 = Wca16_1 + 16384;          // 16384
    float*  cls1A   = (float*)(Wca16_2 + 16384);
    float*  cls1B   = cls1A + 384;
    float*  cls2A   = cls1B + 384;
    float*  cls2B   = cls2A + 384;
    float*  out     = (float*)d_out;

    k_prep<<<322, 256, 0, stream>>>(W_m1a, W_m1b, W_c1a, W_c2a, b_m1a, emb1, emb2,
                                    Wc16, Wb16, Wca16_1, Wca16_2,
                                    cls1A, cls1B, cls2A, cls2B);

    k_fused<<<2*BSZ, 256, 0, stream>>>(state, action,
                                       W_init1, b_init1, W_init2, b_init2,
                                       Wc16, cls1A, cls1B, cls2A, cls2B,
                                       Wb16, b_m1b,
                                       Wca16_1, b_c1a, W_c1b, b_c1b,
                                       Wca16_2, b_c2a, W_c2b, b_c2b,
                                       out);
}